// Round 7
// baseline (297.963 us; speedup 1.0000x reference)
//
#include <hip/hip_runtime.h>
#include <hip/hip_bf16.h>
#include <cstdint>

typedef __attribute__((ext_vector_type(8))) short bf16x8;
typedef __attribute__((ext_vector_type(4))) float f32x4;

#define NCOL 8192
#define YST 36   // y/z row stride in dwords (16B-aligned; b128 reads are 2-way = free)

// ---- workspace layout ----
// uint16 region (bf16 weights, fragment-ordered):
//   AW  [64 m][4 kc][4 qd][8]              -> 8192 el
//   A1  [6 h][64 m][2 kc][4 qd][8]         -> 24576 el
//   AF  [6 h][16 m][2 kc][4 qd][8] (pad)   -> 6144 el
// f32 region (starts at float index 19456): OFSH[64] OFH[384] BIAS[16]
#define WS_AW 0
#define WS_A1 8192
#define WS_AF 32768
#define WS_U16_TOTAL 38912
#define WS_OFSH 19456
#define WS_OFH  19520
#define WS_BIAS 19904

union FragU { uint32_t u[4]; bf16x8 v; uint4 q; };

__device__ __forceinline__ uint32_t rne_bits(float f) {
  uint32_t x = __builtin_bit_cast(uint32_t, f);
  return x + 0x7fffu + ((x >> 16) & 1u);
}
// pack (lo, hi) -> dword with bf16(lo) in low16: 2x v_add3 + 1x v_perm
__device__ __forceinline__ uint32_t pack_bf16(float lo, float hi) {
  return __builtin_amdgcn_perm(rne_bits(hi), rne_bits(lo), 0x07060302u);
}

// ---------------- prep: fold BN into weights, bf16, frag layout (8 el/thread) ----------------
__global__ __launch_bounds__(256) void ch_prep(
    const float* __restrict__ shw, const float* __restrict__ shb,
    const float* __restrict__ shg, const float* __restrict__ shbeta,
    const float* __restrict__ shmean, const float* __restrict__ shvar,
    const float* __restrict__ w1, const float* __restrict__ b1,
    const float* __restrict__ g1, const float* __restrict__ beta1,
    const float* __restrict__ mean1, const float* __restrict__ var1,
    const float* __restrict__ hm_w, const float* __restrict__ hm_b,
    const float* __restrict__ reg_w, const float* __restrict__ reg_b,
    const float* __restrict__ height_w, const float* __restrict__ height_b,
    const float* __restrict__ dim_w, const float* __restrict__ dim_b,
    const float* __restrict__ rot_w, const float* __restrict__ rot_b,
    const float* __restrict__ iou_w, const float* __restrict__ iou_b,
    uint16_t* __restrict__ wsq)
{
  const int tid = blockIdx.x * 256 + threadIdx.x;
  const int rowbase[6] = {0, 3, 5, 6, 9, 11};
  const int couts[6]   = {3, 2, 1, 3, 2, 1};

  if (tid < WS_U16_TOTAL / 8) {
    const int e = tid * 8;
    const float* src = nullptr;
    float sc = 1.f;
    if (e < WS_A1) {                     // AW: e = 128m + 32kc + 8q + i
      const int q = (e >> 3) & 3, kc = (e >> 5) & 3, m = e >> 7;
      sc = shg[m] * rsqrtf(shvar[m] + 1e-5f);
      src = shw + m * 128 + kc * 32 + q * 8;
    } else if (e < WS_AF) {              // A1: e2 = 4096h + 64m + 32kc + 8q + i
      const int e2 = e - WS_A1;
      const int q = (e2 >> 3) & 3, kc = (e2 >> 5) & 1, m = (e2 >> 6) & 63, h = e2 >> 12;
      const int row = h * 64 + m;
      sc = g1[row] * rsqrtf(var1[row] + 1e-5f);
      src = w1 + row * 64 + kc * 32 + q * 8;
    } else {                             // AF: e2 = 1024h + 64m + 32kc + 8q + i
      const int e2 = e - WS_AF;
      const int q = (e2 >> 3) & 3, kc = (e2 >> 5) & 1, m = (e2 >> 6) & 15, h = e2 >> 10;
      const int rr = m - rowbase[h];
      if (rr >= 0 && rr < couts[h]) {
        const float* wp;
        switch (h) {
          case 0: wp = hm_w; break;   case 1: wp = reg_w; break;
          case 2: wp = height_w; break; case 3: wp = dim_w; break;
          case 4: wp = rot_w; break;  default: wp = iou_w; break;
        }
        src = wp + rr * 64 + kc * 32 + q * 8;
      }
    }
    uint4 out;
    if (src) {
      const float4 a = *(const float4*)src;
      const float4 b = *(const float4*)(src + 4);
      out.x = pack_bf16(a.x * sc, a.y * sc);
      out.y = pack_bf16(a.z * sc, a.w * sc);
      out.z = pack_bf16(b.x * sc, b.y * sc);
      out.w = pack_bf16(b.z * sc, b.w * sc);
    } else {
      out = make_uint4(0, 0, 0, 0);
    }
    *(uint4*)(wsq + e) = out;
  } else if (tid < WS_U16_TOTAL / 8 + 464) {
    const int t2 = tid - WS_U16_TOTAL / 8;
    float* wff = (float*)wsq;
    float v = 0.f;
    if (t2 < 64) {
      const float sc = shg[t2] * rsqrtf(shvar[t2] + 1e-5f);
      v = (shb[t2] - shmean[t2]) * sc + shbeta[t2];
    } else if (t2 < 448) {
      const int i = t2 - 64;
      const float sc = g1[i] * rsqrtf(var1[i] + 1e-5f);
      v = (b1[i] - mean1[i]) * sc + beta1[i];
    } else {
      const int i = t2 - 448;
      if (i < 3)       v = hm_b[i];
      else if (i < 5)  v = reg_b[i - 3];
      else if (i < 6)  v = height_b[i - 5];
      else if (i < 9)  v = dim_b[i - 6];
      else if (i < 11) v = rot_b[i - 9];
      else if (i < 12) v = iou_b[i - 11];
    }
    wff[WS_OFSH + t2] = v;
  }
}

// ---------------- main: fused 3-stage, zero barriers, deep-ILP ----------------
__global__ __launch_bounds__(256, 3) void ch_main(
    const float* __restrict__ ct,
    const uint16_t* __restrict__ wsq,
    const float* __restrict__ wsf,
    float* __restrict__ outp)
{
  __shared__ __align__(16) uint32_t sm_y[128 * YST];
  __shared__ __align__(16) uint32_t sm_z[128 * YST];

  const int t    = threadIdx.x;
  const int wv   = t >> 6;
  const int lane = t & 63;
  const int l15  = lane & 15;
  const int qd   = lane >> 4;
  const int bid  = blockIdx.x;
  const int b    = bid >> 6;
  const int col0 = (bid & 63) * 128;
  const int nb   = wv * 32;

  const float* xl = ct + (size_t)b * 128 * NCOL + qd * 8 * NCOL + col0 + nb + l15;

  // ---- stage 1: hoist ALL 64 raw X loads before any pack/MFMA ----
  float r[4][2][8];
  #pragma unroll
  for (int kc = 0; kc < 4; ++kc)
    #pragma unroll
    for (int j = 0; j < 2; ++j)
      #pragma unroll
      for (int i2 = 0; i2 < 4; ++i2) {
        const size_t off = (size_t)((kc * 32 + 2 * i2) * NCOL) + j * 16;
        r[kc][j][2 * i2]     = xl[off];
        r[kc][j][2 * i2 + 1] = xl[off + NCOL];
      }

  f32x4 accY[4][2];
  #pragma unroll
  for (int mt = 0; mt < 4; ++mt)
    #pragma unroll
    for (int j = 0; j < 2; ++j)
      accY[mt][j] = (f32x4){0.f, 0.f, 0.f, 0.f};

  #pragma unroll
  for (int kc = 0; kc < 4; ++kc) {
    FragU aw[4];
    #pragma unroll
    for (int mt = 0; mt < 4; ++mt)
      aw[mt].q = *(const uint4*)(wsq + WS_AW + ((mt * 16 + l15) * 4 + kc) * 32 + qd * 8);
    #pragma unroll
    for (int j = 0; j < 2; ++j) {
      FragU f;
      #pragma unroll
      for (int i2 = 0; i2 < 4; ++i2)
        f.u[i2] = pack_bf16(r[kc][j][2 * i2], r[kc][j][2 * i2 + 1]);
      #pragma unroll
      for (int mt = 0; mt < 4; ++mt)
        accY[mt][j] = __builtin_amdgcn_mfma_f32_16x16x32_bf16(aw[mt].v, f.v, accY[mt][j], 0, 0, 0);
    }
  }

  // stage-1 epilogue: offset + ReLU + pack -> Y_t (wave-private rows)
  #pragma unroll
  for (int mt = 0; mt < 4; ++mt) {
    const f32x4 of = *(const f32x4*)(wsf + WS_OFSH + mt * 16 + qd * 4);
    #pragma unroll
    for (int j = 0; j < 2; ++j) {
      const f32x4 v = accY[mt][j];
      uint2 val;
      val.x = pack_bf16(fmaxf(v[0] + of[0], 0.f), fmaxf(v[1] + of[1], 0.f));
      val.y = pack_bf16(fmaxf(v[2] + of[2], 0.f), fmaxf(v[3] + of[3], 0.f));
      *(uint2*)&sm_y[(nb + j * 16 + l15) * YST + mt * 8 + qd * 2] = val;
    }
  }

  // ---- heads: a1 double-buffered; af issued before z round-trip ----
  FragU a1[2][4][2];
  auto load_a1 = [&](int h, FragU (&d)[4][2]) {
    #pragma unroll
    for (int mt = 0; mt < 4; ++mt)
      #pragma unroll
      for (int kc = 0; kc < 2; ++kc)
        d[mt][kc].q = *(const uint4*)(wsq + WS_A1 + ((h * 64 + mt * 16 + l15) * 2 + kc) * 32 + qd * 8);
  };
  load_a1(0, a1[0]);

  f32x4 accO[2];
  accO[0] = (f32x4){0.f, 0.f, 0.f, 0.f};
  accO[1] = (f32x4){0.f, 0.f, 0.f, 0.f};

  #pragma unroll
  for (int h = 0; h < 6; ++h) {
    const int cur = h & 1;
    if (h < 5) load_a1(h + 1, a1[cur ^ 1]);   // in flight through entire head body

    // stage 2: Z = (sc1.*W1[h]) @ Y
    f32x4 accZ[4][2];
    #pragma unroll
    for (int mt = 0; mt < 4; ++mt)
      #pragma unroll
      for (int j = 0; j < 2; ++j)
        accZ[mt][j] = (f32x4){0.f, 0.f, 0.f, 0.f};

    #pragma unroll
    for (int kc = 0; kc < 2; ++kc) {
      #pragma unroll
      for (int j = 0; j < 2; ++j) {
        FragU f;
        f.q = *(const uint4*)&sm_y[(nb + j * 16 + l15) * YST + kc * 16 + qd * 4];
        #pragma unroll
        for (int mt = 0; mt < 4; ++mt)
          accZ[mt][j] = __builtin_amdgcn_mfma_f32_16x16x32_bf16(a1[cur][mt][kc].v, f.v, accZ[mt][j], 0, 0, 0);
      }
    }

    // issue af loads now; latency hides behind z pack/write/read
    FragU af[2];
    #pragma unroll
    for (int kc = 0; kc < 2; ++kc)
      af[kc].q = *(const uint4*)(wsq + WS_AF + ((h * 16 + l15) * 2 + kc) * 32 + qd * 8);

    // offset + ReLU + pack -> Z_t (wave-private rows)
    #pragma unroll
    for (int mt = 0; mt < 4; ++mt) {
      const f32x4 of = *(const f32x4*)(wsf + WS_OFH + h * 64 + mt * 16 + qd * 4);
      #pragma unroll
      for (int j = 0; j < 2; ++j) {
        const f32x4 v = accZ[mt][j];
        uint2 val;
        val.x = pack_bf16(fmaxf(v[0] + of[0], 0.f), fmaxf(v[1] + of[1], 0.f));
        val.y = pack_bf16(fmaxf(v[2] + of[2], 0.f), fmaxf(v[3] + of[3], 0.f));
        *(uint2*)&sm_z[(nb + j * 16 + l15) * YST + mt * 8 + qd * 2] = val;
      }
    }

    // stage 3: accO += Wf_pad[h] @ Z
    #pragma unroll
    for (int kc = 0; kc < 2; ++kc) {
      #pragma unroll
      for (int j = 0; j < 2; ++j) {
        FragU f;
        f.q = *(const uint4*)&sm_z[(nb + j * 16 + l15) * YST + kc * 16 + qd * 4];
        accO[j] = __builtin_amdgcn_mfma_f32_16x16x32_bf16(af[kc].v, f.v, accO[j], 0, 0, 0);
      }
    }
  }

  // ---- epilogue: bias + store rows 0..11 (f32 out) ----
  if (qd < 3) {
    const f32x4 bs = *(const f32x4*)(wsf + WS_BIAS + qd * 4);
    #pragma unroll
    for (int j = 0; j < 2; ++j) {
      const int col = col0 + nb + j * 16 + l15;
      #pragma unroll
      for (int r2 = 0; r2 < 4; ++r2)
        outp[((size_t)(b * 12 + qd * 4 + r2)) * NCOL + col] = accO[j][r2] + bs[r2];
    }
  }
}

extern "C" void kernel_launch(void* const* d_in, const int* in_sizes, int n_in,
                              void* d_out, int out_size, void* d_ws, size_t ws_size,
                              hipStream_t stream) {
  (void)out_size; (void)ws_size;
  // d_in is in setup_inputs() dict order (round-5 verified); sorted fallback kept.
  static const int sortedPos[25] = {
      0, 24, 19, 21, 20, 22, 23, 8, 3, 5, 4, 6, 7,
      12, 11, 16, 15, 10, 9, 2, 1, 18, 17, 14, 13};
  const bool sorted_order =
      (n_in == 25) && (in_sizes[1] == 3) && (in_sizes[2] == 192) &&
      (in_sizes[8] == 24576) && (in_sizes[24] == 8192);
  const float* p[25];
  for (int r = 0; r < 25; ++r)
    p[r] = (const float*)d_in[sorted_order ? sortedPos[r] : r];

  uint16_t* wsq = (uint16_t*)d_ws;   // needs 79,680 B of d_ws

  hipLaunchKernelGGL(ch_prep, dim3(21), dim3(256), 0, stream,
      p[1], p[2], p[3], p[4], p[5], p[6],
      p[7], p[8], p[9], p[10], p[11], p[12],
      p[13], p[14], p[15], p[16], p[17], p[18],
      p[19], p[20], p[21], p[22], p[23], p[24],
      wsq);

  hipLaunchKernelGGL(ch_main, dim3(2048), dim3(256), 0, stream,
      p[0], (const uint16_t*)wsq, (const float*)wsq, (float*)d_out);
}